// Round 4
// baseline (292.354 us; speedup 1.0000x reference)
//
#include <hip/hip_runtime.h>
#include <math.h>

#define BB 8
#define SS 160
#define HH 768
#define DEPTH 64
#define NHEAD 12
#define DHEAD 64
#define BS (BB*SS)

constexpr float EPS_C = 1e-5f;

// ---------------- Projection: q,k,v = X @ W + b ----------------
__global__ __launch_bounds__(256) void proj_qkv(
    const float* __restrict__ X,
    const float* __restrict__ Wq, const float* __restrict__ bq,
    const float* __restrict__ Wk, const float* __restrict__ bk,
    const float* __restrict__ Wv, const float* __restrict__ bv,
    float* __restrict__ q, float* __restrict__ k, float* __restrict__ v)
{
    __shared__ float sxT[HH * 16];   // 48 KB: sxT[c*16 + r]
    int bx = blockIdx.x;
    int rt = bx / 9, rem = bx % 9;
    int m = rem / 3, ct = rem % 3;
    int row0 = rt * 16;
    const float* W    = (m == 0) ? Wq : (m == 1) ? Wk : Wv;
    const float* bias = (m == 0) ? bq : (m == 1) ? bk : bv;
    float* out        = (m == 0) ? q  : (m == 1) ? k  : v;

    for (int idx = threadIdx.x; idx < 16 * HH; idx += 256) {
        int r = idx / HH, c = idx - r * HH;
        sxT[c * 16 + r] = X[(row0 + r) * HH + c];
    }
    __syncthreads();

    int col = ct * 256 + threadIdx.x;
    float acc[16];
#pragma unroll
    for (int r = 0; r < 16; r++) acc[r] = 0.f;

    const float* Wp = W + col;
    for (int c = 0; c < HH; c++) {
        float wv = Wp[(size_t)c * HH];
        const float4* xp = (const float4*)(&sxT[c * 16]);
        float4 x0 = xp[0], x1 = xp[1], x2 = xp[2], x3 = xp[3];
        acc[0]  += x0.x * wv;  acc[1]  += x0.y * wv;
        acc[2]  += x0.z * wv;  acc[3]  += x0.w * wv;
        acc[4]  += x1.x * wv;  acc[5]  += x1.y * wv;
        acc[6]  += x1.z * wv;  acc[7]  += x1.w * wv;
        acc[8]  += x2.x * wv;  acc[9]  += x2.y * wv;
        acc[10] += x2.z * wv;  acc[11] += x2.w * wv;
        acc[12] += x3.x * wv;  acc[13] += x3.y * wv;
        acc[14] += x3.z * wv;  acc[15] += x3.w * wv;
    }
    float bb = bias[col];
#pragma unroll
    for (int r = 0; r < 16; r++) out[(size_t)(row0 + r) * HH + col] = acc[r] + bb;
}

// ---------------- Fused attention + edge terms + LayerNorm ----------------
// One block per (b, i) query row. 256 threads = 4 waves. Same sync skeleton
// as the validated R2 kernel; masked j skipped via exact p==0 / mask tests.
__global__ __launch_bounds__(256) void attn_kernel(
    const float* __restrict__ token, const float* __restrict__ edge,
    const int* __restrict__ mask,
    const float* __restrict__ q_ws, const float* __restrict__ k_ws,
    const float* __restrict__ v_ws,
    const float* __restrict__ Wek, const float* __restrict__ bek,
    const float* __restrict__ Wev, const float* __restrict__ bev,
    const float* __restrict__ ln_g, const float* __restrict__ ln_b,
    float* __restrict__ out)
{
    __shared__ float  s_q[HH];               // q row; reused as ctx_v after pass2
    __shared__ float  s_qek[NHEAD * DEPTH];  // [h][d] = Wek_h^T q_h
    __shared__ float  s_qbek[NHEAD];         // q_h . bek_h
    __shared__ float2 s_e2[32][33];          // e tile (32 rows), padded
    __shared__ float  s_scores[NHEAD][SS];   // scores -> probs
    __shared__ float  s_pe[NHEAD][DEPTH];    // p . e
    __shared__ float  s_x[HH];               // pre-LN row
    __shared__ int    s_mask[SS];
    __shared__ float  s_red[8];

    int bi = blockIdx.x;                     // b*S + i
    int b  = bi / SS;
    int tid = threadIdx.x;
    int w = tid >> 6, l = tid & 63;

    // ---- load q row + mask row ----
    for (int c = tid; c < HH; c += 256) s_q[c] = q_ws[(size_t)bi * HH + c];
    if (tid < SS) s_mask[tid] = mask[(size_t)bi * SS + tid];
    __syncthreads();

    // ---- qek[h][d] = sum_c q[h*64+c] * Wek[d][h*64+c] ----
    for (int mdx = tid; mdx < NHEAD * DEPTH; mdx += 256) {
        int h = mdx >> 6, d = mdx & 63;
        const float* wp = Wek + (size_t)d * HH + h * DHEAD;
        const float* qp = s_q + h * DHEAD;
        float sum = 0.f;
#pragma unroll
        for (int c = 0; c < DHEAD; c += 4) {
            float4 qv = *(const float4*)(qp + c);
            float4 wv = *(const float4*)(wp + c);
            sum += qv.x * wv.x + qv.y * wv.y + qv.z * wv.z + qv.w * wv.w;
        }
        s_qek[mdx] = sum;
    }
    // qbek[h]: one thread per head
    if (tid < NHEAD) {
        const float* qp = s_q + tid * DHEAD;
        const float* bp = bek + tid * DHEAD;
        float sum = 0.f;
#pragma unroll
        for (int c = 0; c < DHEAD; c++) sum += qp[c] * bp[c];
        s_qbek[tid] = sum;
    }

    const float* e_row = edge + (size_t)bi * SS * DEPTH;
    const float* k_b   = k_ws + (size_t)b * SS * HH;

    // ---- pass 1: scores, j-tiles of 32 (160 = 5*32, no tail) ----
    for (int jt = 0; jt < SS; jt += 32) {
        __syncthreads();   // first iter: covers qek/qbek/mask; later: protects s_e2
        const float2* ep2 = (const float2*)(e_row + (size_t)jt * DEPTH);
        for (int idx = tid; idx < 32 * 32; idx += 256) {
            int jj = idx >> 5, dd = idx & 31;
            s_e2[jj][dd] = s_mask[jt + jj] ? ep2[jj * 32 + dd]
                                           : make_float2(0.f, 0.f);
        }
        __syncthreads();
        for (int item = tid; item < 32 * NHEAD; item += 256) {
            int jj = item & 31, h = item >> 5;
            int j = jt + jj;
            if (!s_mask[j]) { s_scores[h][j] = -10000.0f; continue; }
            const float* kp   = k_b + (size_t)j * HH + h * DHEAD;
            const float* qp   = s_q + h * DHEAD;
            const float* qekp = s_qek + h * DHEAD;
            float sum = 0.f;
#pragma unroll
            for (int d = 0; d < DHEAD; d += 4) {
                float4 kv = *(const float4*)(kp + d);
                float4 qv = *(const float4*)(qp + d);
                float4 qe = *(const float4*)(qekp + d);
                float2 e0 = s_e2[jj][d >> 1];
                float2 e1 = s_e2[jj][(d >> 1) + 1];
                sum += qv.x * kv.x + qv.y * kv.y + qv.z * kv.z + qv.w * kv.w
                     + qe.x * e0.x + qe.y * e0.y + qe.z * e1.x + qe.w * e1.y;
            }
            s_scores[h][j] = (sum + s_qbek[h]) * 0.125f;
        }
    }
    __syncthreads();

    // ---- softmax per head (wave w -> heads w, w+4, w+8); S=160 = 64+64+32 ----
    for (int h = w; h < NHEAD; h += 4) {
        float v0 = s_scores[h][l];
        float v1 = s_scores[h][l + 64];
        float v2 = (l < 32) ? s_scores[h][l + 128] : -INFINITY;
        float mx = fmaxf(v0, fmaxf(v1, v2));
#pragma unroll
        for (int mm = 32; mm >= 1; mm >>= 1) mx = fmaxf(mx, __shfl_xor(mx, mm, 64));
        float e0 = expf(v0 - mx), e1 = expf(v1 - mx);
        float e2 = (l < 32) ? expf(v2 - mx) : 0.f;
        float sm = e0 + e1 + e2;
#pragma unroll
        for (int mm = 32; mm >= 1; mm >>= 1) sm += __shfl_xor(sm, mm, 64);
        float inv = 1.0f / sm;
        s_scores[h][l]      = e0 * inv;
        s_scores[h][l + 64] = e1 * inv;
        if (l < 32) s_scores[h][l + 128] = e2 * inv;
    }
    __syncthreads();

    // ---- pass 2: wave w owns heads 3w..3w+2; lane = channel ----
    // Skip j where all three probs are exactly 0 (masked j underflow to 0,
    // so this is numerically exact; branch is wave-uniform via LDS broadcast).
    {
        int h0 = w * 3;
        float av0 = 0.f, av1 = 0.f, av2 = 0.f;
        float pe0 = 0.f, pe1 = 0.f, pe2 = 0.f;
        const float* vb = v_ws + (size_t)b * SS * HH + h0 * DHEAD + l;
        const float* er = e_row + l;
        const float* p0r = &s_scores[h0][0];
        const float* p1r = &s_scores[h0 + 1][0];
        const float* p2r = &s_scores[h0 + 2][0];
        for (int j = 0; j < SS; j++) {
            float p0 = p0r[j], p1 = p1r[j], p2 = p2r[j];
            if (p0 == 0.f && p1 == 0.f && p2 == 0.f) continue;
            const float* vp = vb + (size_t)j * HH;
            av0 += p0 * vp[0];
            av1 += p1 * vp[DHEAD];
            av2 += p2 * vp[2 * DHEAD];
            float ev = er[(size_t)j * DEPTH];
            pe0 += p0 * ev; pe1 += p1 * ev; pe2 += p2 * ev;
        }
        s_pe[h0][l]     = pe0;
        s_pe[h0 + 1][l] = pe1;
        s_pe[h0 + 2][l] = pe2;
        s_q[h0 * DHEAD + l]       = av0;   // s_q reused as ctx_v
        s_q[(h0 + 1) * DHEAD + l] = av1;
        s_q[(h0 + 2) * DHEAD + l] = av2;
    }
    __syncthreads();

    // ---- ctx_e = pe_h @ Wev_h + bev ; residual add ----
    for (int mdx = tid; mdx < HH; mdx += 256) {
        int h = mdx >> 6;
        const float* pep = &s_pe[h][0];
        float sum = 0.f;
#pragma unroll
        for (int d = 0; d < DEPTH; d++) sum += pep[d] * Wev[(size_t)d * HH + mdx];
        float ctx = s_q[mdx] + (sum + bev[mdx]);
        s_x[mdx] = token[(size_t)bi * HH + mdx] + ctx;
    }
    __syncthreads();

    // ---- LayerNorm over H ----
    float lsum = 0.f, lsq = 0.f;
    for (int c = tid; c < HH; c += 256) {
        float x = s_x[c];
        lsum += x; lsq += x * x;
    }
#pragma unroll
    for (int mm = 32; mm >= 1; mm >>= 1) {
        lsum += __shfl_xor(lsum, mm, 64);
        lsq  += __shfl_xor(lsq,  mm, 64);
    }
    if (l == 0) { s_red[w] = lsum; s_red[4 + w] = lsq; }
    __syncthreads();
    float tsum = s_red[0] + s_red[1] + s_red[2] + s_red[3];
    float tsq  = s_red[4] + s_red[5] + s_red[6] + s_red[7];
    float mu  = tsum / HH;
    float var = tsq / HH - mu * mu;
    float rstd = rsqrtf(var + EPS_C);
    for (int c = tid; c < HH; c += 256)
        out[(size_t)bi * HH + c] = (s_x[c] - mu) * rstd * ln_g[c] + ln_b[c];
}

extern "C" void kernel_launch(void* const* d_in, const int* in_sizes, int n_in,
                              void* d_out, int out_size, void* d_ws, size_t ws_size,
                              hipStream_t stream) {
    const float* token = (const float*)d_in[0];
    const float* edge  = (const float*)d_in[1];
    const int*   mask  = (const int*)d_in[2];
    const float* Wq = (const float*)d_in[3];  const float* bq = (const float*)d_in[4];
    const float* Wk = (const float*)d_in[5];  const float* bk = (const float*)d_in[6];
    const float* Wv = (const float*)d_in[7];  const float* bv = (const float*)d_in[8];
    const float* Wek = (const float*)d_in[9];  const float* bek = (const float*)d_in[10];
    const float* Wev = (const float*)d_in[11]; const float* bev = (const float*)d_in[12];
    const float* ln_g = (const float*)d_in[13]; const float* ln_b = (const float*)d_in[14];
    float* out = (float*)d_out;

    float* q_ws = (float*)d_ws;
    float* k_ws = q_ws + (size_t)BS * HH;
    float* v_ws = k_ws + (size_t)BS * HH;

    proj_qkv<<<720, 256, 0, stream>>>(token, Wq, bq, Wk, bk, Wv, bv,
                                      q_ws, k_ws, v_ws);
    attn_kernel<<<BS, 256, 0, stream>>>(token, edge, mask, q_ws, k_ws, v_ws,
                                        Wek, bek, Wev, bev, ln_g, ln_b, out);
}

// Round 5
// 212.589 us; speedup vs baseline: 1.3752x; 1.3752x over previous
//
#include <hip/hip_runtime.h>
#include <math.h>

#define BB 8
#define SS 160
#define HH 768
#define DEPTH 64
#define NHEAD 12
#define DHEAD 64
#define BS (BB*SS)

constexpr float EPS_C = 1e-5f;

// ---------------- Projection: q,kT,v = X @ W + b ----------------
// k is written TRANSPOSED: kT[b][ch][j] so attn's score loop reads are
// coalesced (lane = j). Each proj thread holds 16 consecutive rows of one
// column in registers -> contiguous 16-float store per thread.
__global__ __launch_bounds__(256) void proj_qkv(
    const float* __restrict__ X,
    const float* __restrict__ Wq, const float* __restrict__ bq,
    const float* __restrict__ Wk, const float* __restrict__ bk,
    const float* __restrict__ Wv, const float* __restrict__ bv,
    float* __restrict__ q, float* __restrict__ kT, float* __restrict__ v)
{
    __shared__ float sxT[HH * 16];   // 48 KB: sxT[c*16 + r]
    int bx = blockIdx.x;
    int rt = bx / 9, rem = bx % 9;
    int m = rem / 3, ct = rem % 3;
    int row0 = rt * 16;
    const float* W    = (m == 0) ? Wq : (m == 1) ? Wk : Wv;
    const float* bias = (m == 0) ? bq : (m == 1) ? bk : bv;

    for (int idx = threadIdx.x; idx < 16 * HH; idx += 256) {
        int r = idx / HH, c = idx - r * HH;
        sxT[c * 16 + r] = X[(row0 + r) * HH + c];
    }
    __syncthreads();

    int col = ct * 256 + threadIdx.x;
    float acc[16];
#pragma unroll
    for (int r = 0; r < 16; r++) acc[r] = 0.f;

    const float* Wp = W + col;
    for (int c = 0; c < HH; c++) {
        float wv = Wp[(size_t)c * HH];
        const float4* xp = (const float4*)(&sxT[c * 16]);
        float4 x0 = xp[0], x1 = xp[1], x2 = xp[2], x3 = xp[3];
        acc[0]  += x0.x * wv;  acc[1]  += x0.y * wv;
        acc[2]  += x0.z * wv;  acc[3]  += x0.w * wv;
        acc[4]  += x1.x * wv;  acc[5]  += x1.y * wv;
        acc[6]  += x1.z * wv;  acc[7]  += x1.w * wv;
        acc[8]  += x2.x * wv;  acc[9]  += x2.y * wv;
        acc[10] += x2.z * wv;  acc[11] += x2.w * wv;
        acc[12] += x3.x * wv;  acc[13] += x3.y * wv;
        acc[14] += x3.z * wv;  acc[15] += x3.w * wv;
    }
    float bb = bias[col];
    if (m == 1) {
        int b  = row0 / SS, i0 = row0 - (row0 / SS) * SS;
        float* dst = kT + ((size_t)b * HH + col) * SS + i0;
#pragma unroll
        for (int r = 0; r < 16; r++) dst[r] = acc[r] + bb;   // 64B contiguous
    } else {
        float* out = (m == 0) ? q : v;
#pragma unroll
        for (int r = 0; r < 16; r++) out[(size_t)(row0 + r) * HH + col] = acc[r] + bb;
    }
}

// ---------------- Fused attention + edge terms + LayerNorm ----------------
// One block per (b, i) query row. 256 threads = 4 waves. Dense compute
// (R2 skeleton); all global reads coalesced via kT layout + 4-lane qek coop.
__global__ __launch_bounds__(256) void attn_kernel(
    const float* __restrict__ token, const float* __restrict__ edge,
    const int* __restrict__ mask,
    const float* __restrict__ q_ws, const float* __restrict__ kT,
    const float* __restrict__ v_ws,
    const float* __restrict__ Wek, const float* __restrict__ bek,
    const float* __restrict__ Wev, const float* __restrict__ bev,
    const float* __restrict__ ln_g, const float* __restrict__ ln_b,
    float* __restrict__ out)
{
    __shared__ float  s_q[HH];               // q row; reused as ctx_v after pass2
    __shared__ float  s_qek[NHEAD * DEPTH];  // [h][d] = Wek_h^T q_h
    __shared__ float  s_qbek[NHEAD];         // q_h . bek_h
    __shared__ float  s_pool[32 * 66];       // e tile [32][66] in pass1; s_x later
    __shared__ float  s_scores[NHEAD][SS];   // scores -> probs
    __shared__ float  s_pe[NHEAD][DEPTH];    // p . e
    __shared__ int    s_mask[SS];
    __shared__ float  s_red[8];

    int bi = blockIdx.x;                     // b*S + i
    int b  = bi / SS;
    int tid = threadIdx.x;
    int w = tid >> 6, l = tid & 63;

    // ---- load q row + mask row ----
    for (int c = tid; c < HH; c += 256) s_q[c] = q_ws[(size_t)bi * HH + c];
    if (tid < SS) s_mask[tid] = mask[(size_t)bi * SS + tid];
    __syncthreads();

    // ---- qek[h][d] = sum_c q[h*64+c] * Wek[d][h*64+c] ----
    // 4 lanes cooperate per output: each handles a 16-c quarter (64B line),
    // so global Wek reads are line-exact coalesced; 2-step shfl combine.
#pragma unroll
    for (int round = 0; round < 12; round++) {
        int lid = round * 256 + tid;         // 0..3071
        int oidx = lid >> 2;                 // 0..767 = h*64+d
        int h = oidx >> 6, d = oidx & 63;
        int c0 = (lid & 3) << 4;
        const float* wp = Wek + (size_t)d * HH + h * DHEAD + c0;
        const float* qp = s_q + h * DHEAD + c0;
        float sum = 0.f;
#pragma unroll
        for (int cc = 0; cc < 16; cc += 4) {
            float4 wv = *(const float4*)(wp + cc);
            float4 qv = *(const float4*)(qp + cc);
            sum += qv.x * wv.x + qv.y * wv.y + qv.z * wv.z + qv.w * wv.w;
        }
        sum += __shfl_xor(sum, 1, 64);
        sum += __shfl_xor(sum, 2, 64);
        if ((lid & 3) == 0) s_qek[oidx] = sum;
    }
    // qbek[h]: one thread per head
    if (tid < NHEAD) {
        const float* qp = s_q + tid * DHEAD;
        const float* bp = bek + tid * DHEAD;
        float sum = 0.f;
#pragma unroll
        for (int c = 0; c < DHEAD; c++) sum += qp[c] * bp[c];
        s_qbek[tid] = sum;
    }

    const float* e_row = edge + (size_t)bi * SS * DEPTH;
    const float* kT_b  = kT + (size_t)b * HH * SS;

    // ---- pass 1: scores, j-tiles of 32 (160 = 5*32) ----
    for (int jt = 0; jt < SS; jt += 32) {
        __syncthreads();   // first iter: covers qek/qbek; later: protects s_pool
        // stage e tile as float2, layout [32][66] (2-way bank alias = free)
        for (int idx = tid; idx < 32 * 32; idx += 256) {
            int jj = idx >> 5, dd = idx & 31;
            *(float2*)(&s_pool[jj * 66 + dd * 2]) =
                *(const float2*)(e_row + (size_t)(jt + jj) * DEPTH + dd * 2);
        }
        __syncthreads();
        for (int item = tid; item < 32 * NHEAD; item += 256) {
            int jj = item & 31, h = item >> 5;
            int j = jt + jj;
            const float* kp   = kT_b + (size_t)(h * DHEAD) * SS + j;  // + d*SS
            const float* qp   = s_q + h * DHEAD;
            const float* qekp = s_qek + h * DHEAD;
            const float* ep   = s_pool + jj * 66;
            float sum = 0.f, sum2 = 0.f;
#pragma unroll
            for (int d = 0; d < DHEAD; d += 4) {
                float k0 = kp[(size_t)d * SS];
                float k1 = kp[(size_t)(d + 1) * SS];
                float k2 = kp[(size_t)(d + 2) * SS];
                float k3 = kp[(size_t)(d + 3) * SS];
                float4 qv = *(const float4*)(qp + d);
                float4 qe = *(const float4*)(qekp + d);
                float2 e0 = *(const float2*)(ep + d);
                float2 e1 = *(const float2*)(ep + d + 2);
                sum  += qv.x * k0 + qv.y * k1 + qv.z * k2 + qv.w * k3;
                sum2 += qe.x * e0.x + qe.y * e0.y + qe.z * e1.x + qe.w * e1.y;
            }
            s_scores[h][j] = s_mask[j] ? (sum + sum2 + s_qbek[h]) * 0.125f
                                       : -10000.0f;
        }
    }
    __syncthreads();

    // ---- softmax per head (wave w -> heads w, w+4, w+8); S=160 = 64+64+32 ----
    for (int h = w; h < NHEAD; h += 4) {
        float v0 = s_scores[h][l];
        float v1 = s_scores[h][l + 64];
        float v2 = (l < 32) ? s_scores[h][l + 128] : -INFINITY;
        float mx = fmaxf(v0, fmaxf(v1, v2));
#pragma unroll
        for (int mm = 32; mm >= 1; mm >>= 1) mx = fmaxf(mx, __shfl_xor(mx, mm, 64));
        float e0 = expf(v0 - mx), e1 = expf(v1 - mx);
        float e2 = (l < 32) ? expf(v2 - mx) : 0.f;
        float sm = e0 + e1 + e2;
#pragma unroll
        for (int mm = 32; mm >= 1; mm >>= 1) sm += __shfl_xor(sm, mm, 64);
        float inv = 1.0f / sm;
        s_scores[h][l]      = e0 * inv;
        s_scores[h][l + 64] = e1 * inv;
        if (l < 32) s_scores[h][l + 128] = e2 * inv;
    }
    __syncthreads();

    // ---- pass 2: wave w owns heads 3w..3w+2; lane = channel; dense ----
    {
        int h0 = w * 3;
        float av0 = 0.f, av1 = 0.f, av2 = 0.f;
        float pe0 = 0.f, pe1 = 0.f, pe2 = 0.f;
        const float* vb = v_ws + (size_t)b * SS * HH + h0 * DHEAD + l;
        const float* er = e_row + l;
        const float* p0r = &s_scores[h0][0];
        const float* p1r = &s_scores[h0 + 1][0];
        const float* p2r = &s_scores[h0 + 2][0];
#pragma unroll 4
        for (int j = 0; j < SS; j++) {
            float p0 = p0r[j], p1 = p1r[j], p2 = p2r[j];
            const float* vp = vb + (size_t)j * HH;
            av0 += p0 * vp[0];
            av1 += p1 * vp[DHEAD];
            av2 += p2 * vp[2 * DHEAD];
            float ev = er[(size_t)j * DEPTH];
            pe0 += p0 * ev; pe1 += p1 * ev; pe2 += p2 * ev;
        }
        s_pe[h0][l]     = pe0;
        s_pe[h0 + 1][l] = pe1;
        s_pe[h0 + 2][l] = pe2;
        s_q[h0 * DHEAD + l]       = av0;   // s_q reused as ctx_v
        s_q[(h0 + 1) * DHEAD + l] = av1;
        s_q[(h0 + 2) * DHEAD + l] = av2;
    }
    __syncthreads();

    // ---- ctx_e = pe_h @ Wev_h + bev ; residual add (s_x = s_pool alias) ----
    float* s_x = s_pool;
    for (int mdx = tid; mdx < HH; mdx += 256) {
        int h = mdx >> 6;
        const float* pep = &s_pe[h][0];
        float sum = 0.f;
#pragma unroll
        for (int d = 0; d < DEPTH; d++) sum += pep[d] * Wev[(size_t)d * HH + mdx];
        float ctx = s_q[mdx] + (sum + bev[mdx]);
        s_x[mdx] = token[(size_t)bi * HH + mdx] + ctx;
    }
    __syncthreads();

    // ---- LayerNorm over H ----
    float lsum = 0.f, lsq = 0.f;
    for (int c = tid; c < HH; c += 256) {
        float x = s_x[c];
        lsum += x; lsq += x * x;
    }
#pragma unroll
    for (int mm = 32; mm >= 1; mm >>= 1) {
        lsum += __shfl_xor(lsum, mm, 64);
        lsq  += __shfl_xor(lsq,  mm, 64);
    }
    if (l == 0) { s_red[w] = lsum; s_red[4 + w] = lsq; }
    __syncthreads();
    float tsum = s_red[0] + s_red[1] + s_red[2] + s_red[3];
    float tsq  = s_red[4] + s_red[5] + s_red[6] + s_red[7];
    float mu  = tsum / HH;
    float var = tsq / HH - mu * mu;
    float rstd = rsqrtf(var + EPS_C);
    for (int c = tid; c < HH; c += 256)
        out[(size_t)bi * HH + c] = (s_x[c] - mu) * rstd * ln_g[c] + ln_b[c];
}

extern "C" void kernel_launch(void* const* d_in, const int* in_sizes, int n_in,
                              void* d_out, int out_size, void* d_ws, size_t ws_size,
                              hipStream_t stream) {
    const float* token = (const float*)d_in[0];
    const float* edge  = (const float*)d_in[1];
    const int*   mask  = (const int*)d_in[2];
    const float* Wq = (const float*)d_in[3];  const float* bq = (const float*)d_in[4];
    const float* Wk = (const float*)d_in[5];  const float* bk = (const float*)d_in[6];
    const float* Wv = (const float*)d_in[7];  const float* bv = (const float*)d_in[8];
    const float* Wek = (const float*)d_in[9];  const float* bek = (const float*)d_in[10];
    const float* Wev = (const float*)d_in[11]; const float* bev = (const float*)d_in[12];
    const float* ln_g = (const float*)d_in[13]; const float* ln_b = (const float*)d_in[14];
    float* out = (float*)d_out;

    float* q_ws  = (float*)d_ws;
    float* kT_ws = q_ws + (size_t)BS * HH;
    float* v_ws  = kT_ws + (size_t)BS * HH;

    proj_qkv<<<720, 256, 0, stream>>>(token, Wq, bq, Wk, bk, Wv, bv,
                                      q_ws, kT_ws, v_ws);
    attn_kernel<<<BS, 256, 0, stream>>>(token, edge, mask, q_ws, kT_ws, v_ws,
                                        Wek, bek, Wev, bev, ln_g, ln_b, out);
}